// Round 2
// baseline (1233.992 us; speedup 1.0000x reference)
//
#include <hip/hip_runtime.h>
#include <stdint.h>

#define NN 50000
#define EE 1600000
#define IN_DIMC 256
#define HIDC 128
#define EPSC 1e-5f

// ---------------------------------------------------------------------------
// GEMM: C[M,128] = A1@W1 (+ A2@W2) + bias.  A row-major [M,K], W row-major
// [K,128]. Tile 64 rows x 128 cols, Kc=64, 256 threads, 4x8 micro-tile.
// Optional: per-column affine+relu applied to A1 on load (preStats != null,
// requires K1==128). Always: fused column sum/sumsq into outStats.
// ---------------------------------------------------------------------------
__global__ __launch_bounds__(256) void gemm_kernel(
    const float* __restrict__ A1, const float* __restrict__ W1, int K1,
    const float* __restrict__ A2, const float* __restrict__ W2, int K2,
    const float* __restrict__ bias, float* __restrict__ C, int M,
    const float* __restrict__ preStats, const float* __restrict__ preG,
    const float* __restrict__ preBe, float* __restrict__ outStats)
{
    __shared__ float As[64][68];
    __shared__ float Bs[64][132];
    __shared__ float aArr[128], bArr[128];

    const int t  = threadIdx.x;
    const int tr = t >> 4;   // 0..15
    const int tc = t & 15;   // 0..15
    const int row0 = blockIdx.x * 64;
    const int doAffine = (preStats != nullptr);

    if (doAffine && t < 128) {
        const float invM = 1.0f / (float)M;
        const float mean = preStats[t] * invM;
        float var = preStats[128 + t] * invM - mean * mean;
        if (var < 0.0f) var = 0.0f;
        const float s = preG[t] / sqrtf(var + EPSC);
        aArr[t] = s;
        bArr[t] = preBe[t] - mean * s;
    }
    if (doAffine) __syncthreads();

    float acc[4][8];
    #pragma unroll
    for (int i = 0; i < 4; i++)
        #pragma unroll
        for (int j = 0; j < 8; j++) acc[i][j] = 0.0f;

    for (int s = 0; s < 2; s++) {
        const float* A = s ? A2 : A1;
        const float* W = s ? W2 : W1;
        const int    K = s ? K2 : K1;
        if (A == nullptr) continue;

        for (int kc = 0; kc < K; kc += 64) {
            {
                const int lr  = t >> 4;
                const int lc4 = t & 15;
                #pragma unroll
                for (int p = 0; p < 4; p++) {
                    const int r  = lr + p * 16;
                    int gr = row0 + r;
                    if (gr > M - 1) gr = M - 1;  // clamp; bogus rows never stored
                    float4 v = *(const float4*)(A + (size_t)gr * K + kc + lc4 * 4);
                    if (doAffine && s == 0) {
                        const int k0 = kc + lc4 * 4;
                        v.x = fmaxf(aArr[k0]     * v.x + bArr[k0],     0.0f);
                        v.y = fmaxf(aArr[k0 + 1] * v.y + bArr[k0 + 1], 0.0f);
                        v.z = fmaxf(aArr[k0 + 2] * v.z + bArr[k0 + 2], 0.0f);
                        v.w = fmaxf(aArr[k0 + 3] * v.w + bArr[k0 + 3], 0.0f);
                    }
                    *(float4*)&As[r][lc4 * 4] = v;
                }
            }
            {
                const int lk  = t >> 5;
                const int wc4 = t & 31;
                #pragma unroll
                for (int p = 0; p < 8; p++) {
                    const int k = lk + p * 8;
                    const float4 v = *(const float4*)(W + (size_t)(kc + k) * HIDC + wc4 * 4);
                    *(float4*)&Bs[k][wc4 * 4] = v;
                }
            }
            __syncthreads();

            #pragma unroll 4
            for (int k = 0; k < 64; k++) {
                const float a0 = As[tr * 4 + 0][k];
                const float a1 = As[tr * 4 + 1][k];
                const float a2 = As[tr * 4 + 2][k];
                const float a3 = As[tr * 4 + 3][k];
                const float4 b0 = *(const float4*)&Bs[k][tc * 8];
                const float4 b1 = *(const float4*)&Bs[k][tc * 8 + 4];
                acc[0][0] += a0 * b0.x; acc[0][1] += a0 * b0.y; acc[0][2] += a0 * b0.z; acc[0][3] += a0 * b0.w;
                acc[0][4] += a0 * b1.x; acc[0][5] += a0 * b1.y; acc[0][6] += a0 * b1.z; acc[0][7] += a0 * b1.w;
                acc[1][0] += a1 * b0.x; acc[1][1] += a1 * b0.y; acc[1][2] += a1 * b0.z; acc[1][3] += a1 * b0.w;
                acc[1][4] += a1 * b1.x; acc[1][5] += a1 * b1.y; acc[1][6] += a1 * b1.z; acc[1][7] += a1 * b1.w;
                acc[2][0] += a2 * b0.x; acc[2][1] += a2 * b0.y; acc[2][2] += a2 * b0.z; acc[2][3] += a2 * b0.w;
                acc[2][4] += a2 * b1.x; acc[2][5] += a2 * b1.y; acc[2][6] += a2 * b1.z; acc[2][7] += a2 * b1.w;
                acc[3][0] += a3 * b0.x; acc[3][1] += a3 * b0.y; acc[3][2] += a3 * b0.z; acc[3][3] += a3 * b0.w;
                acc[3][4] += a3 * b1.x; acc[3][5] += a3 * b1.y; acc[3][6] += a3 * b1.z; acc[3][7] += a3 * b1.w;
            }
            __syncthreads();
        }
    }

    // bias add + validity
    const float4 bv0 = *(const float4*)(bias + tc * 8);
    const float4 bv1 = *(const float4*)(bias + tc * 8 + 4);
    float ob[4][8];
    int valid[4];
    #pragma unroll
    for (int i = 0; i < 4; i++) {
        valid[i] = (row0 + tr * 4 + i) < M;
        ob[i][0] = acc[i][0] + bv0.x; ob[i][1] = acc[i][1] + bv0.y;
        ob[i][2] = acc[i][2] + bv0.z; ob[i][3] = acc[i][3] + bv0.w;
        ob[i][4] = acc[i][4] + bv1.x; ob[i][5] = acc[i][5] + bv1.y;
        ob[i][6] = acc[i][6] + bv1.z; ob[i][7] = acc[i][7] + bv1.w;
    }

    // fused column stats (sum / sumsq over this block's valid rows)
    float ls[8], lq[8];
    #pragma unroll
    for (int j = 0; j < 8; j++) { ls[j] = 0.0f; lq[j] = 0.0f; }
    #pragma unroll
    for (int i = 0; i < 4; i++) {
        if (valid[i]) {
            #pragma unroll
            for (int j = 0; j < 8; j++) {
                ls[j] += ob[i][j];
                lq[j] += ob[i][j] * ob[i][j];
            }
        }
    }
    __syncthreads();  // done with As/Bs tiles; reuse as reduction scratch
    float (*Ss)[136] = reinterpret_cast<float(*)[136]>(&As[0][0]);
    float (*Sq)[136] = reinterpret_cast<float(*)[136]>(&Bs[0][0]);
    #pragma unroll
    for (int j = 0; j < 8; j++) {
        Ss[tr][tc * 8 + j] = ls[j];
        Sq[tr][tc * 8 + j] = lq[j];
    }
    __syncthreads();
    #pragma unroll
    for (int st = 8; st > 0; st >>= 1) {
        if (tr < st) {
            #pragma unroll
            for (int j = 0; j < 8; j++) {
                const int c = tc * 8 + j;
                Ss[tr][c] += Ss[tr + st][c];
                Sq[tr][c] += Sq[tr + st][c];
            }
        }
        __syncthreads();
    }
    if (tr == 0) {
        #pragma unroll
        for (int j = 0; j < 8; j++) {
            const int c = tc * 8 + j;
            atomicAdd(&outStats[c],       Ss[0][c]);
            atomicAdd(&outStats[128 + c], Sq[0][c]);
        }
    }

    // store
    #pragma unroll
    for (int i = 0; i < 4; i++) {
        if (valid[i]) {
            const int gr = row0 + tr * 4 + i;
            *(float4*)(C + (size_t)gr * HIDC + tc * 8)     = *(float4*)&ob[i][0];
            *(float4*)(C + (size_t)gr * HIDC + tc * 8 + 4) = *(float4*)&ob[i][4];
        }
    }
}

// ---------------------------------------------------------------------------
// BN apply (+ optional relu)
// ---------------------------------------------------------------------------
__global__ __launch_bounds__(256) void bn_apply_kernel(
    const float* __restrict__ src, float* __restrict__ dst,
    const float* __restrict__ stats, const float* __restrict__ gamma,
    const float* __restrict__ beta, int relu, int M)
{
    __shared__ float sc[128], sh[128];
    const int t = threadIdx.x;
    if (t < 128) {
        const float invM = 1.0f / (float)M;
        const float mean = stats[t] * invM;
        float var = stats[128 + t] * invM - mean * mean;
        if (var < 0.0f) var = 0.0f;
        const float s = gamma[t] / sqrtf(var + EPSC);
        sc[t] = s;
        sh[t] = beta[t] - mean * s;
    }
    __syncthreads();

    const int total4 = M * HIDC / 4;
    for (int i = blockIdx.x * 256 + t; i < total4; i += gridDim.x * 256) {
        float4 v = ((const float4*)src)[i];
        const int c = (i * 4) & 127;
        v.x = v.x * sc[c]     + sh[c];
        v.y = v.y * sc[c + 1] + sh[c + 1];
        v.z = v.z * sc[c + 2] + sh[c + 2];
        v.w = v.w * sc[c + 3] + sh[c + 3];
        if (relu) {
            v.x = fmaxf(v.x, 0.0f); v.y = fmaxf(v.y, 0.0f);
            v.z = fmaxf(v.z, 0.0f); v.w = fmaxf(v.w, 0.0f);
        }
        ((float4*)dst)[i] = v;
    }
}

// ---------------------------------------------------------------------------
// Fold BN3 affine into SAGE2 weights:
//   Wf[k][j] = a[k]*W[k][j];  bf[j] = bl[j] + sum_k b[k]*(Wl[k][j]+Wr[k][j])
// ---------------------------------------------------------------------------
__global__ __launch_bounds__(256) void fold_kernel(
    const float* __restrict__ stats, const float* __restrict__ g,
    const float* __restrict__ be, const float* __restrict__ Wl,
    const float* __restrict__ Wr, const float* __restrict__ bl,
    float* __restrict__ Wfl, float* __restrict__ Wfr, float* __restrict__ bf)
{
    __shared__ float a[128], b[128];
    const int t = threadIdx.x;
    if (t < 128) {
        const float invM = 1.0f / (float)NN;
        const float mean = stats[t] * invM;
        float var = stats[128 + t] * invM - mean * mean;
        if (var < 0.0f) var = 0.0f;
        const float s = g[t] / sqrtf(var + EPSC);
        a[t] = s;
        b[t] = be[t] - mean * s;
    }
    __syncthreads();
    for (int idx = t; idx < 128 * 128; idx += 256) {
        const int k = idx >> 7;
        Wfl[idx] = a[k] * Wl[idx];
        Wfr[idx] = a[k] * Wr[idx];
    }
    if (t < 128) {
        float s = bl[t];
        for (int k = 0; k < 128; k++)
            s += b[k] * (Wl[k * 128 + t] + Wr[k * 128 + t]);
        bf[t] = s;
    }
}

// ---------------------------------------------------------------------------
// CSR build: hist (atomics, capture rank) -> 2-level scan -> atomic-free scatter
// ---------------------------------------------------------------------------
__global__ void hist_kernel(const int* __restrict__ dstArr,
                            int* __restrict__ deg, int* __restrict__ rank)
{
    for (int e = blockIdx.x * blockDim.x + threadIdx.x; e < EE;
         e += gridDim.x * blockDim.x)
        rank[e] = atomicAdd(&deg[dstArr[e]], 1);
}

__global__ __launch_bounds__(256) void scanA_kernel(
    const int* __restrict__ deg, int* __restrict__ tmp, int* __restrict__ blockSums)
{
    __shared__ int wtot[4];
    const int t = threadIdx.x;
    const int lane = t & 63, w = t >> 6;
    const int i = blockIdx.x * 256 + t;
    const int v = (i < NN) ? deg[i] : 0;
    int x = v;
    #pragma unroll
    for (int off = 1; off < 64; off <<= 1) {
        const int y = __shfl_up(x, off);
        if (lane >= off) x += y;
    }
    if (lane == 63) wtot[w] = x;
    __syncthreads();
    int woff = 0;
    #pragma unroll
    for (int j = 0; j < 4; j++) if (j < w) woff += wtot[j];
    const int incl = x + woff;
    if (i < NN) tmp[i] = incl;
    if (t == 255) blockSums[blockIdx.x] = incl;
}

__global__ __launch_bounds__(256) void scanB_kernel(
    int* __restrict__ blockSums, int* __restrict__ blockOffs,
    int* __restrict__ rowp, int nB)
{
    __shared__ int wtot[4];
    const int t = threadIdx.x;
    const int lane = t & 63, w = t >> 6;
    const int v = (t < nB) ? blockSums[t] : 0;
    int x = v;
    #pragma unroll
    for (int off = 1; off < 64; off <<= 1) {
        const int y = __shfl_up(x, off);
        if (lane >= off) x += y;
    }
    if (lane == 63) wtot[w] = x;
    __syncthreads();
    int woff = 0;
    #pragma unroll
    for (int j = 0; j < 4; j++) if (j < w) woff += wtot[j];
    const int incl = x + woff;
    if (t < nB) blockOffs[t] = incl - v;   // exclusive
    if (t == 255) rowp[NN] = incl;          // grand total (pads are 0)
}

__global__ __launch_bounds__(256) void scanC_kernel(
    const int* __restrict__ tmp, const int* __restrict__ deg,
    const int* __restrict__ blockOffs, int* __restrict__ rowp)
{
    const int i = blockIdx.x * 256 + threadIdx.x;
    if (i < NN) rowp[i] = tmp[i] - deg[i] + blockOffs[blockIdx.x];
}

__global__ void scatter_kernel(const int* __restrict__ srcArr,
                               const int* __restrict__ dstArr,
                               const int* __restrict__ rank,
                               const int* __restrict__ rowp,
                               int* __restrict__ col)
{
    for (int e = blockIdx.x * blockDim.x + threadIdx.x; e < EE;
         e += gridDim.x * blockDim.x) {
        const int d = dstArr[e];
        col[rowp[d] + rank[e]] = srcArr[e];
    }
}

// ---------------------------------------------------------------------------
// Mean aggregation: one wave per node; lane holds float2
// ---------------------------------------------------------------------------
__global__ __launch_bounds__(256) void agg_kernel(
    const float* __restrict__ F, const int* __restrict__ row_ptr,
    const int* __restrict__ col, float* __restrict__ Mout)
{
    const int lane = threadIdx.x & 63;
    const int wave = blockIdx.x * (blockDim.x >> 6) + (threadIdx.x >> 6);
    const int nwaves = gridDim.x * (blockDim.x >> 6);

    for (int n = wave; n < NN; n += nwaves) {
        const int b = row_ptr[n];
        const int e = row_ptr[n + 1];
        const int deg = e - b;
        float accx = 0.0f, accy = 0.0f;
        int j = b;
        while (j < e) {
            const int m = (e - j < 64) ? (e - j) : 64;
            const int idx = (lane < m) ? col[j + lane] : 0;
            #pragma unroll 4
            for (int u = 0; u < m; u++) {
                const int s = __shfl(idx, u);
                const float2 v = *(const float2*)(F + (size_t)s * HIDC + lane * 2);
                accx += v.x; accy += v.y;
            }
            j += m;
        }
        const float inv = 1.0f / (float)(deg > 1 ? deg : 1);
        float2 r; r.x = accx * inv; r.y = accy * inv;
        *(float2*)(Mout + (size_t)n * HIDC + lane * 2) = r;
    }
}

// ---------------------------------------------------------------------------
extern "C" void kernel_launch(void* const* d_in, const int* in_sizes, int n_in,
                              void* d_out, int out_size, void* d_ws, size_t ws_size,
                              hipStream_t stream)
{
    const float* x     = (const float*)d_in[0];
    const int*   ei    = (const int*)  d_in[1];
    const float* W_in  = (const float*)d_in[2];
    const float* b_in  = (const float*)d_in[3];
    const float* g1    = (const float*)d_in[4];
    const float* be1   = (const float*)d_in[5];
    const float* W_hid = (const float*)d_in[6];
    const float* b_hid = (const float*)d_in[7];
    const float* g2    = (const float*)d_in[8];
    const float* be2   = (const float*)d_in[9];
    const float* Wl1   = (const float*)d_in[10];
    const float* bl1   = (const float*)d_in[11];
    const float* Wr1   = (const float*)d_in[12];
    const float* g3    = (const float*)d_in[13];
    const float* be3   = (const float*)d_in[14];
    const float* Wl2   = (const float*)d_in[15];
    const float* bl2   = (const float*)d_in[16];
    const float* Wr2   = (const float*)d_in[17];
    const float* g4    = (const float*)d_in[18];
    const float* be4   = (const float*)d_in[19];

    const int* srcArr = ei;        // edge_index[0]
    const int* dstArr = ei + EE;   // edge_index[1]

    char* ws = (char*)d_ws;
    float* bufA      = (float*)ws; ws += (size_t)NN * HIDC * sizeof(float);
    float* bufB      = (float*)ws; ws += (size_t)NN * HIDC * sizeof(float);
    float* stats     = (float*)ws; ws += 4 * 256 * sizeof(float);
    int*   deg       = (int*)ws;   ws += (size_t)NN * sizeof(int);
    int*   rowp      = (int*)ws;   ws += (size_t)(NN + 4) * sizeof(int);
    int*   colIdx    = (int*)ws;   ws += (size_t)EE * sizeof(int);
    int*   tmpScan   = (int*)ws;   ws += (size_t)NN * sizeof(int);
    int*   blockSums = (int*)ws;   ws += 256 * sizeof(int);
    int*   blockOffs = (int*)ws;   ws += 256 * sizeof(int);
    float* Wfl2      = (float*)ws; ws += 128 * 128 * sizeof(float);
    float* Wfr2      = (float*)ws; ws += 128 * 128 * sizeof(float);
    float* bf2       = (float*)ws; ws += 128 * sizeof(float);
    // rank aliases bufB: CSR build (hist->scatter) fully precedes first bufB write
    int* rank = (int*)bufB;

    float* out0 = (float*)d_out;             // feat  [NN*HID]
    float* out1 = out0 + (size_t)NN * HIDC;  // out   [NN*HID]

    // zero stats (4 stages) + deg — contiguous region, one memset
    hipMemsetAsync(stats, 0, 4 * 256 * sizeof(float) + (size_t)NN * sizeof(int), stream);

    // CSR build
    hist_kernel<<<2048, 256, 0, stream>>>(dstArr, deg, rank);
    const int nScanB = (NN + 255) / 256;   // 196
    scanA_kernel<<<nScanB, 256, 0, stream>>>(deg, tmpScan, blockSums);
    scanB_kernel<<<1, 256, 0, stream>>>(blockSums, blockOffs, rowp, nScanB);
    scanC_kernel<<<nScanB, 256, 0, stream>>>(tmpScan, deg, blockOffs, rowp);
    scatter_kernel<<<2048, 256, 0, stream>>>(srcArr, dstArr, rank, rowp, colIdx);

    const int gemmGrid = (NN + 63) / 64;   // 782

    // stage 1: input linear -> bufA (raw) + stats1
    gemm_kernel<<<gemmGrid, 256, 0, stream>>>(x, W_in, IN_DIMC, nullptr, nullptr, 0,
                                              b_in, bufA, NN,
                                              nullptr, nullptr, nullptr, stats + 0);
    // stage 2: hidden linear with fused BN1+relu on A-load -> bufB (raw) + stats2
    gemm_kernel<<<gemmGrid, 256, 0, stream>>>(bufA, W_hid, HIDC, nullptr, nullptr, 0,
                                              b_hid, bufB, NN,
                                              stats + 0, g1, be1, stats + 256);
    // BN2+relu apply -> out0 (feat)
    bn_apply_kernel<<<1024, 256, 0, stream>>>(bufB, out0, stats + 256, g2, be2, 1, NN);

    // stage 3: SAGE1 -> bufB (raw) + stats3
    agg_kernel<<<4096, 256, 0, stream>>>(out0, rowp, colIdx, bufA);
    gemm_kernel<<<gemmGrid, 256, 0, stream>>>(bufA, Wl1, HIDC, out0, Wr1, HIDC,
                                              bl1, bufB, NN,
                                              nullptr, nullptr, nullptr, stats + 512);

    // fold BN3 into SAGE2 weights
    fold_kernel<<<1, 256, 0, stream>>>(stats + 512, g3, be3, Wl2, Wr2, bl2,
                                       Wfl2, Wfr2, bf2);

    // stage 4: SAGE2 on raw stage-3 output (BN3 folded into weights) -> out1 + stats4
    agg_kernel<<<4096, 256, 0, stream>>>(bufB, rowp, colIdx, bufA);
    gemm_kernel<<<gemmGrid, 256, 0, stream>>>(bufA, Wfl2, HIDC, bufB, Wfr2, HIDC,
                                              bf2, out1, NN,
                                              nullptr, nullptr, nullptr, stats + 768);
    // BN4 apply -> out1
    bn_apply_kernel<<<1024, 256, 0, stream>>>(out1, out1, stats + 768, g4, be4, 0, NN);
}

// Round 3
// 607.846 us; speedup vs baseline: 2.0301x; 2.0301x over previous
//
#include <hip/hip_runtime.h>
#include <stdint.h>

#define NN 50000
#define EE 1600000
#define IN_DIMC 256
#define HIDC 128
#define EPSC 1e-5f

typedef unsigned short ushort_t;
typedef __attribute__((ext_vector_type(8))) short short8;
typedef __attribute__((ext_vector_type(4))) float floatx4;

static __device__ inline ushort_t f2bf(float f) {
    unsigned int u = __float_as_uint(f);
    u = u + 0x7fffu + ((u >> 16) & 1u);   // RNE
    return (ushort_t)(u >> 16);
}
static __device__ inline unsigned int pack2(float a, float b) {
    return (unsigned int)f2bf(a) | ((unsigned int)f2bf(b) << 16);
}
static __device__ inline float bf2f(unsigned int bits16) {
    return __uint_as_float(bits16 << 16);
}

// ---------------------------------------------------------------------------
// Weight transpose + bf16 convert: Wt[n][k] = bf16(W[k][n]).  W is [K][128].
// ---------------------------------------------------------------------------
__global__ __launch_bounds__(256) void tcvt_kernel(
    const float* __restrict__ W, ushort_t* __restrict__ Wt, int K)
{
    const int idx = blockIdx.x * 256 + threadIdx.x;
    if (idx < 128 * K) {
        const int n = idx / K;
        const int k = idx - n * K;
        Wt[idx] = f2bf(W[(size_t)k * 128 + n]);
    }
}

// ---------------------------------------------------------------------------
// MFMA GEMM: C[M,128] = A1@W1 (+ A2@W2) + bias, fp32 accum, bf16 inputs.
//  - A1 type: a1type==0 -> fp32 [M,K1] (optionally BN-affine+relu on load),
//             a1type==1 -> bf16 [M,K1]
//  - A2 (optional) always bf16 [M,K2]
//  - Wt1/Wt2: bf16, TRANSPOSED [128][K] (n-major, k-contiguous)
//  - fused column sum/sumsq into outStats[0..127]=sum, [128..255]=sumsq
// Tile: 64 rows x 128 cols, 4 waves in 2x2 (m,n) split, k-chunk 64.
// mfma_f32_16x16x32_bf16; A/B frag [lane&15][quad*8+j]; C/D col=lane&15,
// row=quad*4+reg (m89-verified layouts).
// ---------------------------------------------------------------------------
__global__ __launch_bounds__(256) void mfma_gemm_kernel(
    const void* __restrict__ A1, const ushort_t* __restrict__ Wt1, int K1, int a1type,
    const void* __restrict__ A2, const ushort_t* __restrict__ Wt2, int K2,
    const float* __restrict__ bias, float* __restrict__ C, int M,
    const float* __restrict__ preStats, const float* __restrict__ preG,
    const float* __restrict__ preBe, float* __restrict__ outStats)
{
    __shared__ ushort_t As[64 * 72];    // 64 rows x 64 k, pad 8 -> 9216 B
    __shared__ ushort_t Bs[128 * 72];   // 128 n  x 64 k, pad 8 -> 18432 B
    __shared__ float aArr[128], bArr[128];
    __shared__ float red_s[4][64], red_q[4][64];

    const int t     = threadIdx.x;
    const int lane  = t & 63;
    const int wave  = t >> 6;
    const int quad  = lane >> 4;
    const int l15   = lane & 15;
    const int mhalf = wave & 1;     // rows mhalf*32 .. +31
    const int nhalf = wave >> 1;    // cols nhalf*64 .. +63
    const int row0  = blockIdx.x * 64;
    const int doAffine = (preStats != nullptr);

    if (doAffine && t < 128) {
        const float invM = 1.0f / (float)M;
        const float mean = preStats[t] * invM;
        float var = preStats[128 + t] * invM - mean * mean;
        if (var < 0.0f) var = 0.0f;
        const float s = preG[t] / sqrtf(var + EPSC);
        aArr[t] = s;
        bArr[t] = preBe[t] - mean * s;
    }
    if (doAffine) __syncthreads();

    floatx4 acc[2][4];
    #pragma unroll
    for (int i = 0; i < 2; i++)
        #pragma unroll
        for (int j = 0; j < 4; j++)
            acc[i][j] = (floatx4){0.0f, 0.0f, 0.0f, 0.0f};

    for (int s = 0; s < 2; s++) {
        const void*     A     = s ? A2  : A1;
        const ushort_t* Wt    = s ? Wt2 : Wt1;
        const int       K     = s ? K2  : K1;
        const int       atype = s ? 1   : a1type;
        if (A == nullptr) continue;

        for (int kc = 0; kc < K; kc += 64) {
            // ---- stage A tile: 64x64 bf16, 8 bf16 (16 B) per thread-pass, 2 passes
            #pragma unroll
            for (int p = 0; p < 2; p++) {
                const int idx = p * 256 + t;
                const int r   = idx >> 3;          // 0..63
                const int c0  = (idx & 7) * 8;     // 0..56
                int gr = row0 + r;
                if (gr > M - 1) gr = M - 1;        // clamp; never stored
                if (atype == 0) {
                    const float* Af = (const float*)A;
                    const size_t base = (size_t)gr * K + kc + c0;
                    float4 v0 = *(const float4*)(Af + base);
                    float4 v1 = *(const float4*)(Af + base + 4);
                    if (doAffine && s == 0) {
                        const int k0 = kc + c0;
                        v0.x = fmaxf(aArr[k0]     * v0.x + bArr[k0],     0.0f);
                        v0.y = fmaxf(aArr[k0 + 1] * v0.y + bArr[k0 + 1], 0.0f);
                        v0.z = fmaxf(aArr[k0 + 2] * v0.z + bArr[k0 + 2], 0.0f);
                        v0.w = fmaxf(aArr[k0 + 3] * v0.w + bArr[k0 + 3], 0.0f);
                        v1.x = fmaxf(aArr[k0 + 4] * v1.x + bArr[k0 + 4], 0.0f);
                        v1.y = fmaxf(aArr[k0 + 5] * v1.y + bArr[k0 + 5], 0.0f);
                        v1.z = fmaxf(aArr[k0 + 6] * v1.z + bArr[k0 + 6], 0.0f);
                        v1.w = fmaxf(aArr[k0 + 7] * v1.w + bArr[k0 + 7], 0.0f);
                    }
                    uint4 w;
                    w.x = pack2(v0.x, v0.y);
                    w.y = pack2(v0.z, v0.w);
                    w.z = pack2(v1.x, v1.y);
                    w.w = pack2(v1.z, v1.w);
                    *(uint4*)(As + r * 72 + c0) = w;
                } else {
                    const ushort_t* Ab = (const ushort_t*)A;
                    *(uint4*)(As + r * 72 + c0) =
                        *(const uint4*)(Ab + (size_t)gr * K + kc + c0);
                }
            }
            // ---- stage B tile: 128x64 bf16, 4 passes
            #pragma unroll
            for (int p = 0; p < 4; p++) {
                const int idx = p * 256 + t;
                const int n   = idx >> 3;          // 0..127
                const int c0  = (idx & 7) * 8;
                *(uint4*)(Bs + n * 72 + c0) =
                    *(const uint4*)(Wt + (size_t)n * K + kc + c0);
            }
            __syncthreads();

            #pragma unroll
            for (int ks = 0; ks < 2; ks++) {
                const int ko = ks * 32 + quad * 8;
                const short8 a0 = *(const short8*)(As + (mhalf * 32 + l15) * 72 + ko);
                const short8 a1 = *(const short8*)(As + (mhalf * 32 + 16 + l15) * 72 + ko);
                short8 b[4];
                #pragma unroll
                for (int j = 0; j < 4; j++)
                    b[j] = *(const short8*)(Bs + (nhalf * 64 + j * 16 + l15) * 72 + ko);
                #pragma unroll
                for (int j = 0; j < 4; j++) {
                    acc[0][j] = __builtin_amdgcn_mfma_f32_16x16x32_bf16(a0, b[j], acc[0][j], 0, 0, 0);
                    acc[1][j] = __builtin_amdgcn_mfma_f32_16x16x32_bf16(a1, b[j], acc[1][j], 0, 0, 0);
                }
            }
            __syncthreads();
        }
    }

    // ---- epilogue: bias add, store fp32 C, fused column stats
    float s_[4], q_[4];
    #pragma unroll
    for (int j = 0; j < 4; j++) { s_[j] = 0.0f; q_[j] = 0.0f; }

    #pragma unroll
    for (int j = 0; j < 4; j++) {
        const int col = nhalf * 64 + j * 16 + l15;
        const float bv = bias[col];
        #pragma unroll
        for (int i = 0; i < 2; i++) {
            const int rbase = row0 + mhalf * 32 + i * 16 + quad * 4;
            #pragma unroll
            for (int reg = 0; reg < 4; reg++) {
                const float val = acc[i][j][reg] + bv;
                const int r_ = rbase + reg;
                if (r_ < M) {
                    C[(size_t)r_ * HIDC + col] = val;
                    s_[j] += val;
                    q_[j] += val * val;
                }
            }
        }
    }
    // reduce across the 4 quads (same col within wave)
    #pragma unroll
    for (int j = 0; j < 4; j++) {
        s_[j] += __shfl_xor(s_[j], 16, 64);
        s_[j] += __shfl_xor(s_[j], 32, 64);
        q_[j] += __shfl_xor(q_[j], 16, 64);
        q_[j] += __shfl_xor(q_[j], 32, 64);
    }
    if (quad == 0) {
        #pragma unroll
        for (int j = 0; j < 4; j++) {
            red_s[wave][j * 16 + l15] = s_[j];
            red_q[wave][j * 16 + l15] = q_[j];
        }
    }
    __syncthreads();
    if (t < 128) {
        const int c = t;
        const int g = c >> 6;              // which wave pair (nhalf)
        const int cc = c & 63;
        const float S = red_s[g * 2][cc] + red_s[g * 2 + 1][cc];
        const float Q = red_q[g * 2][cc] + red_q[g * 2 + 1][cc];
        atomicAdd(&outStats[c], S);
        atomicAdd(&outStats[128 + c], Q);
    }
}

// ---------------------------------------------------------------------------
// BN apply: dst fp32 (optional) and/or dst bf16 (optional), + optional relu
// ---------------------------------------------------------------------------
__global__ __launch_bounds__(256) void bn_apply_kernel(
    const float* __restrict__ src, float* __restrict__ dstF,
    ushort_t* __restrict__ dstB, const float* __restrict__ stats,
    const float* __restrict__ gamma, const float* __restrict__ beta,
    int relu, int M)
{
    __shared__ float sc[128], sh[128];
    const int t = threadIdx.x;
    if (t < 128) {
        const float invM = 1.0f / (float)M;
        const float mean = stats[t] * invM;
        float var = stats[128 + t] * invM - mean * mean;
        if (var < 0.0f) var = 0.0f;
        const float s = gamma[t] / sqrtf(var + EPSC);
        sc[t] = s;
        sh[t] = beta[t] - mean * s;
    }
    __syncthreads();

    const int total4 = M * HIDC / 4;
    for (int i = blockIdx.x * 256 + t; i < total4; i += gridDim.x * 256) {
        float4 v = ((const float4*)src)[i];
        const int c = (i * 4) & 127;
        v.x = v.x * sc[c]     + sh[c];
        v.y = v.y * sc[c + 1] + sh[c + 1];
        v.z = v.z * sc[c + 2] + sh[c + 2];
        v.w = v.w * sc[c + 3] + sh[c + 3];
        if (relu) {
            v.x = fmaxf(v.x, 0.0f); v.y = fmaxf(v.y, 0.0f);
            v.z = fmaxf(v.z, 0.0f); v.w = fmaxf(v.w, 0.0f);
        }
        if (dstF) ((float4*)dstF)[i] = v;
        if (dstB) {
            uint2 w;
            w.x = pack2(v.x, v.y);
            w.y = pack2(v.z, v.w);
            *(uint2*)(dstB + (size_t)i * 4) = w;
        }
    }
}

// ---------------------------------------------------------------------------
// CSR build: hist (atomics, capture rank) -> 2-level scan -> atomic-free scatter
// ---------------------------------------------------------------------------
__global__ void hist_kernel(const int* __restrict__ dstArr,
                            int* __restrict__ deg, int* __restrict__ rank)
{
    for (int e = blockIdx.x * blockDim.x + threadIdx.x; e < EE;
         e += gridDim.x * blockDim.x)
        rank[e] = atomicAdd(&deg[dstArr[e]], 1);
}

__global__ __launch_bounds__(256) void scanA_kernel(
    const int* __restrict__ deg, int* __restrict__ tmp, int* __restrict__ blockSums)
{
    __shared__ int wtot[4];
    const int t = threadIdx.x;
    const int lane = t & 63, w = t >> 6;
    const int i = blockIdx.x * 256 + t;
    const int v = (i < NN) ? deg[i] : 0;
    int x = v;
    #pragma unroll
    for (int off = 1; off < 64; off <<= 1) {
        const int y = __shfl_up(x, off);
        if (lane >= off) x += y;
    }
    if (lane == 63) wtot[w] = x;
    __syncthreads();
    int woff = 0;
    #pragma unroll
    for (int j = 0; j < 4; j++) if (j < w) woff += wtot[j];
    const int incl = x + woff;
    if (i < NN) tmp[i] = incl;
    if (t == 255) blockSums[blockIdx.x] = incl;
}

__global__ __launch_bounds__(256) void scanB_kernel(
    int* __restrict__ blockSums, int* __restrict__ blockOffs,
    int* __restrict__ rowp, int nB)
{
    __shared__ int wtot[4];
    const int t = threadIdx.x;
    const int lane = t & 63, w = t >> 6;
    const int v = (t < nB) ? blockSums[t] : 0;
    int x = v;
    #pragma unroll
    for (int off = 1; off < 64; off <<= 1) {
        const int y = __shfl_up(x, off);
        if (lane >= off) x += y;
    }
    if (lane == 63) wtot[w] = x;
    __syncthreads();
    int woff = 0;
    #pragma unroll
    for (int j = 0; j < 4; j++) if (j < w) woff += wtot[j];
    const int incl = x + woff;
    if (t < nB) blockOffs[t] = incl - v;   // exclusive
    if (t == 255) rowp[NN] = incl;
}

__global__ __launch_bounds__(256) void scanC_kernel(
    const int* __restrict__ tmp, const int* __restrict__ deg,
    const int* __restrict__ blockOffs, int* __restrict__ rowp)
{
    const int i = blockIdx.x * 256 + threadIdx.x;
    if (i < NN) rowp[i] = tmp[i] - deg[i] + blockOffs[blockIdx.x];
}

__global__ void scatter_kernel(const int* __restrict__ srcArr,
                               const int* __restrict__ dstArr,
                               const int* __restrict__ rank,
                               const int* __restrict__ rowp,
                               int* __restrict__ col)
{
    for (int e = blockIdx.x * blockDim.x + threadIdx.x; e < EE;
         e += gridDim.x * blockDim.x) {
        const int d = dstArr[e];
        col[rowp[d] + rank[e]] = srcArr[e];
    }
}

// ---------------------------------------------------------------------------
// Mean aggregation over bf16 features: one wave per node, 2 cols/lane (4 B)
// ---------------------------------------------------------------------------
__global__ __launch_bounds__(256) void agg_kernel(
    const ushort_t* __restrict__ F, const int* __restrict__ row_ptr,
    const int* __restrict__ col, ushort_t* __restrict__ Mout)
{
    const int lane = threadIdx.x & 63;
    const int wave = blockIdx.x * (blockDim.x >> 6) + (threadIdx.x >> 6);
    const int nwaves = gridDim.x * (blockDim.x >> 6);

    for (int n = wave; n < NN; n += nwaves) {
        const int b = row_ptr[n];
        const int e = row_ptr[n + 1];
        const int deg = e - b;
        float accx = 0.0f, accy = 0.0f;
        int j = b;
        while (j < e) {
            const int m = (e - j < 64) ? (e - j) : 64;
            const int idx = (lane < m) ? col[j + lane] : 0;
            #pragma unroll 4
            for (int u = 0; u < m; u++) {
                const int s = __shfl(idx, u);
                const unsigned int v = *(const unsigned int*)(F + (size_t)s * HIDC + lane * 2);
                accx += bf2f(v & 0xffffu);
                accy += bf2f(v >> 16);
            }
            j += m;
        }
        const float inv = 1.0f / (float)(deg > 1 ? deg : 1);
        *(unsigned int*)(Mout + (size_t)n * HIDC + lane * 2) =
            pack2(accx * inv, accy * inv);
    }
}

// ---------------------------------------------------------------------------
extern "C" void kernel_launch(void* const* d_in, const int* in_sizes, int n_in,
                              void* d_out, int out_size, void* d_ws, size_t ws_size,
                              hipStream_t stream)
{
    const float* x     = (const float*)d_in[0];
    const int*   ei    = (const int*)  d_in[1];
    const float* W_in  = (const float*)d_in[2];
    const float* b_in  = (const float*)d_in[3];
    const float* g1    = (const float*)d_in[4];
    const float* be1   = (const float*)d_in[5];
    const float* W_hid = (const float*)d_in[6];
    const float* b_hid = (const float*)d_in[7];
    const float* g2    = (const float*)d_in[8];
    const float* be2   = (const float*)d_in[9];
    const float* Wl1   = (const float*)d_in[10];
    const float* bl1   = (const float*)d_in[11];
    const float* Wr1   = (const float*)d_in[12];
    const float* g3    = (const float*)d_in[13];
    const float* be3   = (const float*)d_in[14];
    const float* Wl2   = (const float*)d_in[15];
    const float* bl2   = (const float*)d_in[16];
    const float* Wr2   = (const float*)d_in[17];
    const float* g4    = (const float*)d_in[18];
    const float* be4   = (const float*)d_in[19];

    const int* srcArr = ei;        // edge_index[0]
    const int* dstArr = ei + EE;   // edge_index[1]

    char* ws = (char*)d_ws;
    float*    bufA      = (float*)ws;    ws += (size_t)NN * HIDC * sizeof(float);
    float*    bufB      = (float*)ws;    ws += (size_t)NN * HIDC * sizeof(float);
    ushort_t* featB16   = (ushort_t*)ws; ws += (size_t)NN * HIDC * sizeof(ushort_t);
    ushort_t* o3B16     = (ushort_t*)ws; ws += (size_t)NN * HIDC * sizeof(ushort_t);
    ushort_t* aggB16    = (ushort_t*)ws; ws += (size_t)NN * HIDC * sizeof(ushort_t);
    float*    stats     = (float*)ws;    ws += 4 * 256 * sizeof(float);
    int*      deg       = (int*)ws;      ws += (size_t)NN * sizeof(int);
    int*      rowp      = (int*)ws;      ws += (size_t)(NN + 4) * sizeof(int);
    int*      colIdx    = (int*)ws;      ws += (size_t)EE * sizeof(int);
    int*      tmpScan   = (int*)ws;      ws += (size_t)NN * sizeof(int);
    int*      blockSums = (int*)ws;      ws += 256 * sizeof(int);
    int*      blockOffs = (int*)ws;      ws += 256 * sizeof(int);
    ushort_t* Wt_in     = (ushort_t*)ws; ws += 128 * 256 * sizeof(ushort_t);
    ushort_t* Wt_hid    = (ushort_t*)ws; ws += 128 * 128 * sizeof(ushort_t);
    ushort_t* Wtl1      = (ushort_t*)ws; ws += 128 * 128 * sizeof(ushort_t);
    ushort_t* Wtr1      = (ushort_t*)ws; ws += 128 * 128 * sizeof(ushort_t);
    ushort_t* Wtl2      = (ushort_t*)ws; ws += 128 * 128 * sizeof(ushort_t);
    ushort_t* Wtr2      = (ushort_t*)ws; ws += 128 * 128 * sizeof(ushort_t);
    // rank aliases bufA: CSR build (hist->scatter) fully precedes first bufA write
    int* rank = (int*)bufA;

    float* out0 = (float*)d_out;             // feat  [NN*HID] fp32
    float* out1 = out0 + (size_t)NN * HIDC;  // out   [NN*HID] fp32

    // zero stats (4 stages) + deg — contiguous, one memset
    hipMemsetAsync(stats, 0, 4 * 256 * sizeof(float) + (size_t)NN * sizeof(int), stream);

    // weight transpose + bf16 convert
    tcvt_kernel<<<128, 256, 0, stream>>>(W_in,  Wt_in,  256);
    tcvt_kernel<<<64,  256, 0, stream>>>(W_hid, Wt_hid, 128);
    tcvt_kernel<<<64,  256, 0, stream>>>(Wl1,   Wtl1,   128);
    tcvt_kernel<<<64,  256, 0, stream>>>(Wr1,   Wtr1,   128);
    tcvt_kernel<<<64,  256, 0, stream>>>(Wl2,   Wtl2,   128);
    tcvt_kernel<<<64,  256, 0, stream>>>(Wr2,   Wtr2,   128);

    // CSR build
    hist_kernel<<<2048, 256, 0, stream>>>(dstArr, deg, rank);
    const int nScanB = (NN + 255) / 256;   // 196
    scanA_kernel<<<nScanB, 256, 0, stream>>>(deg, tmpScan, blockSums);
    scanB_kernel<<<1, 256, 0, stream>>>(blockSums, blockOffs, rowp, nScanB);
    scanC_kernel<<<nScanB, 256, 0, stream>>>(tmpScan, deg, blockOffs, rowp);
    scatter_kernel<<<2048, 256, 0, stream>>>(srcArr, dstArr, rank, rowp, colIdx);

    const int gemmGrid = (NN + 63) / 64;   // 782

    // stage 1: input linear (x fp32, K=256) -> bufA fp32 + stats0
    mfma_gemm_kernel<<<gemmGrid, 256, 0, stream>>>(
        x, Wt_in, IN_DIMC, 0, nullptr, nullptr, 0,
        b_in, bufA, NN, nullptr, nullptr, nullptr, stats + 0);

    // stage 2: hidden linear, BN1+relu fused on A-load -> bufB fp32 + stats1
    mfma_gemm_kernel<<<gemmGrid, 256, 0, stream>>>(
        bufA, Wt_hid, HIDC, 0, nullptr, nullptr, 0,
        b_hid, bufB, NN, stats + 0, g1, be1, stats + 256);

    // BN2+relu -> out0 (fp32) + featB16 (bf16)
    bn_apply_kernel<<<1024, 256, 0, stream>>>(bufB, out0, featB16,
                                              stats + 256, g2, be2, 1, NN);

    // stage 3: SAGE1
    agg_kernel<<<4096, 256, 0, stream>>>(featB16, rowp, colIdx, aggB16);
    mfma_gemm_kernel<<<gemmGrid, 256, 0, stream>>>(
        aggB16, Wtl1, HIDC, 1, featB16, Wtr1, HIDC,
        bl1, bufA, NN, nullptr, nullptr, nullptr, stats + 512);

    // BN3 -> o3B16 (bf16 only)
    bn_apply_kernel<<<1024, 256, 0, stream>>>(bufA, nullptr, o3B16,
                                              stats + 512, g3, be3, 0, NN);

    // stage 4: SAGE2
    agg_kernel<<<4096, 256, 0, stream>>>(o3B16, rowp, colIdx, aggB16);
    mfma_gemm_kernel<<<gemmGrid, 256, 0, stream>>>(
        aggB16, Wtl2, HIDC, 1, o3B16, Wtr2, HIDC,
        bl2, bufB, NN, nullptr, nullptr, nullptr, stats + 768);

    // BN4 -> out1 (fp32)
    bn_apply_kernel<<<1024, 256, 0, stream>>>(bufB, out1, nullptr,
                                              stats + 768, g4, be4, 0, NN);
}

// Round 4
// 501.087 us; speedup vs baseline: 2.4626x; 1.2131x over previous
//
#include <hip/hip_runtime.h>
#include <stdint.h>

#define NN 50000
#define EE 1600000
#define IN_DIMC 256
#define HIDC 128
#define EPSC 1e-5f

typedef unsigned short ushort_t;
typedef __attribute__((ext_vector_type(8))) short short8;
typedef __attribute__((ext_vector_type(4))) float floatx4;

static __device__ inline ushort_t f2bf(float f) {
    unsigned int u = __float_as_uint(f);
    u = u + 0x7fffu + ((u >> 16) & 1u);   // RNE
    return (ushort_t)(u >> 16);
}
static __device__ inline unsigned int pack2(float a, float b) {
    return (unsigned int)f2bf(a) | ((unsigned int)f2bf(b) << 16);
}
static __device__ inline float bf2f(unsigned int bits16) {
    return __uint_as_float(bits16 << 16);
}

// ---------------------------------------------------------------------------
// Weight transpose + bf16 convert: Wt[n][k] = bf16(W[k][n]).  W is [K][128].
// ---------------------------------------------------------------------------
__global__ __launch_bounds__(256) void tcvt_kernel(
    const float* __restrict__ W, ushort_t* __restrict__ Wt, int K)
{
    const int idx = blockIdx.x * 256 + threadIdx.x;
    if (idx < 128 * K) {
        const int n = idx / K;
        const int k = idx - n * K;
        Wt[idx] = f2bf(W[(size_t)k * 128 + n]);
    }
}

// ---------------------------------------------------------------------------
// MFMA GEMM: C[M,128] = A1@W1 (+ A2@W2) + bias, fp32 accum, bf16 inputs.
// (unchanged from round 3 — verified)
// ---------------------------------------------------------------------------
__global__ __launch_bounds__(256) void mfma_gemm_kernel(
    const void* __restrict__ A1, const ushort_t* __restrict__ Wt1, int K1, int a1type,
    const void* __restrict__ A2, const ushort_t* __restrict__ Wt2, int K2,
    const float* __restrict__ bias, float* __restrict__ C, int M,
    const float* __restrict__ preStats, const float* __restrict__ preG,
    const float* __restrict__ preBe, float* __restrict__ outStats)
{
    __shared__ ushort_t As[64 * 72];
    __shared__ ushort_t Bs[128 * 72];
    __shared__ float aArr[128], bArr[128];
    __shared__ float red_s[4][64], red_q[4][64];

    const int t     = threadIdx.x;
    const int lane  = t & 63;
    const int wave  = t >> 6;
    const int quad  = lane >> 4;
    const int l15   = lane & 15;
    const int mhalf = wave & 1;
    const int nhalf = wave >> 1;
    const int row0  = blockIdx.x * 64;
    const int doAffine = (preStats != nullptr);

    if (doAffine && t < 128) {
        const float invM = 1.0f / (float)M;
        const float mean = preStats[t] * invM;
        float var = preStats[128 + t] * invM - mean * mean;
        if (var < 0.0f) var = 0.0f;
        const float s = preG[t] / sqrtf(var + EPSC);
        aArr[t] = s;
        bArr[t] = preBe[t] - mean * s;
    }
    if (doAffine) __syncthreads();

    floatx4 acc[2][4];
    #pragma unroll
    for (int i = 0; i < 2; i++)
        #pragma unroll
        for (int j = 0; j < 4; j++)
            acc[i][j] = (floatx4){0.0f, 0.0f, 0.0f, 0.0f};

    for (int s = 0; s < 2; s++) {
        const void*     A     = s ? A2  : A1;
        const ushort_t* Wt    = s ? Wt2 : Wt1;
        const int       K     = s ? K2  : K1;
        const int       atype = s ? 1   : a1type;
        if (A == nullptr) continue;

        for (int kc = 0; kc < K; kc += 64) {
            #pragma unroll
            for (int p = 0; p < 2; p++) {
                const int idx = p * 256 + t;
                const int r   = idx >> 3;
                const int c0  = (idx & 7) * 8;
                int gr = row0 + r;
                if (gr > M - 1) gr = M - 1;
                if (atype == 0) {
                    const float* Af = (const float*)A;
                    const size_t base = (size_t)gr * K + kc + c0;
                    float4 v0 = *(const float4*)(Af + base);
                    float4 v1 = *(const float4*)(Af + base + 4);
                    if (doAffine && s == 0) {
                        const int k0 = kc + c0;
                        v0.x = fmaxf(aArr[k0]     * v0.x + bArr[k0],     0.0f);
                        v0.y = fmaxf(aArr[k0 + 1] * v0.y + bArr[k0 + 1], 0.0f);
                        v0.z = fmaxf(aArr[k0 + 2] * v0.z + bArr[k0 + 2], 0.0f);
                        v0.w = fmaxf(aArr[k0 + 3] * v0.w + bArr[k0 + 3], 0.0f);
                        v1.x = fmaxf(aArr[k0 + 4] * v1.x + bArr[k0 + 4], 0.0f);
                        v1.y = fmaxf(aArr[k0 + 5] * v1.y + bArr[k0 + 5], 0.0f);
                        v1.z = fmaxf(aArr[k0 + 6] * v1.z + bArr[k0 + 6], 0.0f);
                        v1.w = fmaxf(aArr[k0 + 7] * v1.w + bArr[k0 + 7], 0.0f);
                    }
                    uint4 w;
                    w.x = pack2(v0.x, v0.y);
                    w.y = pack2(v0.z, v0.w);
                    w.z = pack2(v1.x, v1.y);
                    w.w = pack2(v1.z, v1.w);
                    *(uint4*)(As + r * 72 + c0) = w;
                } else {
                    const ushort_t* Ab = (const ushort_t*)A;
                    *(uint4*)(As + r * 72 + c0) =
                        *(const uint4*)(Ab + (size_t)gr * K + kc + c0);
                }
            }
            #pragma unroll
            for (int p = 0; p < 4; p++) {
                const int idx = p * 256 + t;
                const int n   = idx >> 3;
                const int c0  = (idx & 7) * 8;
                *(uint4*)(Bs + n * 72 + c0) =
                    *(const uint4*)(Wt + (size_t)n * K + kc + c0);
            }
            __syncthreads();

            #pragma unroll
            for (int ks = 0; ks < 2; ks++) {
                const int ko = ks * 32 + quad * 8;
                const short8 a0 = *(const short8*)(As + (mhalf * 32 + l15) * 72 + ko);
                const short8 a1 = *(const short8*)(As + (mhalf * 32 + 16 + l15) * 72 + ko);
                short8 b[4];
                #pragma unroll
                for (int j = 0; j < 4; j++)
                    b[j] = *(const short8*)(Bs + (nhalf * 64 + j * 16 + l15) * 72 + ko);
                #pragma unroll
                for (int j = 0; j < 4; j++) {
                    acc[0][j] = __builtin_amdgcn_mfma_f32_16x16x32_bf16(a0, b[j], acc[0][j], 0, 0, 0);
                    acc[1][j] = __builtin_amdgcn_mfma_f32_16x16x32_bf16(a1, b[j], acc[1][j], 0, 0, 0);
                }
            }
            __syncthreads();
        }
    }

    float s_[4], q_[4];
    #pragma unroll
    for (int j = 0; j < 4; j++) { s_[j] = 0.0f; q_[j] = 0.0f; }

    #pragma unroll
    for (int j = 0; j < 4; j++) {
        const int col = nhalf * 64 + j * 16 + l15;
        const float bv = bias[col];
        #pragma unroll
        for (int i = 0; i < 2; i++) {
            const int rbase = row0 + mhalf * 32 + i * 16 + quad * 4;
            #pragma unroll
            for (int reg = 0; reg < 4; reg++) {
                const float val = acc[i][j][reg] + bv;
                const int r_ = rbase + reg;
                if (r_ < M) {
                    C[(size_t)r_ * HIDC + col] = val;
                    s_[j] += val;
                    q_[j] += val * val;
                }
            }
        }
    }
    #pragma unroll
    for (int j = 0; j < 4; j++) {
        s_[j] += __shfl_xor(s_[j], 16, 64);
        s_[j] += __shfl_xor(s_[j], 32, 64);
        q_[j] += __shfl_xor(q_[j], 16, 64);
        q_[j] += __shfl_xor(q_[j], 32, 64);
    }
    if (quad == 0) {
        #pragma unroll
        for (int j = 0; j < 4; j++) {
            red_s[wave][j * 16 + l15] = s_[j];
            red_q[wave][j * 16 + l15] = q_[j];
        }
    }
    __syncthreads();
    if (t < 128) {
        const int c = t;
        const int g = c >> 6;
        const int cc = c & 63;
        const float S = red_s[g * 2][cc] + red_s[g * 2 + 1][cc];
        const float Q = red_q[g * 2][cc] + red_q[g * 2 + 1][cc];
        atomicAdd(&outStats[c], S);
        atomicAdd(&outStats[128 + c], Q);
    }
}

// ---------------------------------------------------------------------------
// BN apply: dst fp32 (optional) and/or dst bf16 (optional), + optional relu
// ---------------------------------------------------------------------------
__global__ __launch_bounds__(256) void bn_apply_kernel(
    const float* __restrict__ src, float* __restrict__ dstF,
    ushort_t* __restrict__ dstB, const float* __restrict__ stats,
    const float* __restrict__ gamma, const float* __restrict__ beta,
    int relu, int M)
{
    __shared__ float sc[128], sh[128];
    const int t = threadIdx.x;
    if (t < 128) {
        const float invM = 1.0f / (float)M;
        const float mean = stats[t] * invM;
        float var = stats[128 + t] * invM - mean * mean;
        if (var < 0.0f) var = 0.0f;
        const float s = gamma[t] / sqrtf(var + EPSC);
        sc[t] = s;
        sh[t] = beta[t] - mean * s;
    }
    __syncthreads();

    const int total4 = M * HIDC / 4;
    for (int i = blockIdx.x * 256 + t; i < total4; i += gridDim.x * 256) {
        float4 v = ((const float4*)src)[i];
        const int c = (i * 4) & 127;
        v.x = v.x * sc[c]     + sh[c];
        v.y = v.y * sc[c + 1] + sh[c + 1];
        v.z = v.z * sc[c + 2] + sh[c + 2];
        v.w = v.w * sc[c + 3] + sh[c + 3];
        if (relu) {
            v.x = fmaxf(v.x, 0.0f); v.y = fmaxf(v.y, 0.0f);
            v.z = fmaxf(v.z, 0.0f); v.w = fmaxf(v.w, 0.0f);
        }
        if (dstF) ((float4*)dstF)[i] = v;
        if (dstB) {
            uint2 w;
            w.x = pack2(v.x, v.y);
            w.y = pack2(v.z, v.w);
            *(uint2*)(dstB + (size_t)i * 4) = w;
        }
    }
}

// ---------------------------------------------------------------------------
// CSR build, XCD-sharded histogram:
//   deg8[c][n] private per shard c=blockIdx&7 (XCD-local atomics);
//   rank[e] = (c<<24) | local_rank; cumdeg merges planes.
// ---------------------------------------------------------------------------
__global__ __launch_bounds__(256) void hist_kernel(
    const int* __restrict__ dstArr, int* __restrict__ deg8, int* __restrict__ rank)
{
    const int c = blockIdx.x & 7;
    int* deg = deg8 + (size_t)c * NN;
    const int4* d4 = (const int4*)dstArr;
    int4* r4 = (int4*)rank;
    const int n4 = EE / 4;
    for (int i = blockIdx.x * blockDim.x + threadIdx.x; i < n4;
         i += gridDim.x * blockDim.x) {
        const int4 d = d4[i];
        int4 r;
        r.x = atomicAdd(&deg[d.x], 1) | (c << 24);
        r.y = atomicAdd(&deg[d.y], 1) | (c << 24);
        r.z = atomicAdd(&deg[d.z], 1) | (c << 24);
        r.w = atomicAdd(&deg[d.w], 1) | (c << 24);
        r4[i] = r;
    }
}

// deg[n] = sum_c deg8[c][n]; cum8[c][n] = sum_{c'<c} deg8[c'][n]
__global__ __launch_bounds__(256) void cumdeg_kernel(
    const int* __restrict__ deg8, int* __restrict__ deg, int* __restrict__ cum8)
{
    const int i = blockIdx.x * 256 + threadIdx.x;
    if (i < NN) {
        int s = 0;
        #pragma unroll
        for (int c = 0; c < 8; c++) {
            cum8[(size_t)c * NN + i] = s;
            s += deg8[(size_t)c * NN + i];
        }
        deg[i] = s;
    }
}

__global__ __launch_bounds__(256) void scanA_kernel(
    const int* __restrict__ deg, int* __restrict__ tmp, int* __restrict__ blockSums)
{
    __shared__ int wtot[4];
    const int t = threadIdx.x;
    const int lane = t & 63, w = t >> 6;
    const int i = blockIdx.x * 256 + t;
    const int v = (i < NN) ? deg[i] : 0;
    int x = v;
    #pragma unroll
    for (int off = 1; off < 64; off <<= 1) {
        const int y = __shfl_up(x, off);
        if (lane >= off) x += y;
    }
    if (lane == 63) wtot[w] = x;
    __syncthreads();
    int woff = 0;
    #pragma unroll
    for (int j = 0; j < 4; j++) if (j < w) woff += wtot[j];
    const int incl = x + woff;
    if (i < NN) tmp[i] = incl;
    if (t == 255) blockSums[blockIdx.x] = incl;
}

__global__ __launch_bounds__(256) void scanB_kernel(
    int* __restrict__ blockSums, int* __restrict__ blockOffs,
    int* __restrict__ rowp, int nB)
{
    __shared__ int wtot[4];
    const int t = threadIdx.x;
    const int lane = t & 63, w = t >> 6;
    const int v = (t < nB) ? blockSums[t] : 0;
    int x = v;
    #pragma unroll
    for (int off = 1; off < 64; off <<= 1) {
        const int y = __shfl_up(x, off);
        if (lane >= off) x += y;
    }
    if (lane == 63) wtot[w] = x;
    __syncthreads();
    int woff = 0;
    #pragma unroll
    for (int j = 0; j < 4; j++) if (j < w) woff += wtot[j];
    const int incl = x + woff;
    if (t < nB) blockOffs[t] = incl - v;
    if (t == 255) rowp[NN] = incl;
}

__global__ __launch_bounds__(256) void scanC_kernel(
    const int* __restrict__ tmp, const int* __restrict__ deg,
    const int* __restrict__ blockOffs, int* __restrict__ rowp)
{
    const int i = blockIdx.x * 256 + threadIdx.x;
    if (i < NN) rowp[i] = tmp[i] - deg[i] + blockOffs[blockIdx.x];
}

__global__ __launch_bounds__(256) void scatter_kernel(
    const int* __restrict__ srcArr, const int* __restrict__ dstArr,
    const int* __restrict__ rank, const int* __restrict__ rowp,
    const int* __restrict__ cum8, int* __restrict__ col)
{
    const int4* s4 = (const int4*)srcArr;
    const int4* d4 = (const int4*)dstArr;
    const int4* r4 = (const int4*)rank;
    const int n4 = EE / 4;
    for (int i = blockIdx.x * blockDim.x + threadIdx.x; i < n4;
         i += gridDim.x * blockDim.x) {
        const int4 s = s4[i];
        const int4 d = d4[i];
        const int4 r = r4[i];
        {
            const int c = (unsigned)r.x >> 24, lr = r.x & 0xFFFFFF;
            col[rowp[d.x] + cum8[(size_t)c * NN + d.x] + lr] = s.x;
        }
        {
            const int c = (unsigned)r.y >> 24, lr = r.y & 0xFFFFFF;
            col[rowp[d.y] + cum8[(size_t)c * NN + d.y] + lr] = s.y;
        }
        {
            const int c = (unsigned)r.z >> 24, lr = r.z & 0xFFFFFF;
            col[rowp[d.z] + cum8[(size_t)c * NN + d.z] + lr] = s.z;
        }
        {
            const int c = (unsigned)r.w >> 24, lr = r.w & 0xFFFFFF;
            col[rowp[d.w] + cum8[(size_t)c * NN + d.w] + lr] = s.w;
        }
    }
}

// ---------------------------------------------------------------------------
// Mean aggregation over bf16 features: one wave per node, 2 cols/lane (4 B).
// Wave-uniform CSR bounds forced into SGPRs -> index loads become scalar
// (s_load), removing the per-edge bpermute from the address chain; unroll 8
// keeps 8 gathers in flight.
// ---------------------------------------------------------------------------
__global__ __launch_bounds__(256) void agg_kernel(
    const ushort_t* __restrict__ F, const int* __restrict__ row_ptr,
    const int* __restrict__ col, ushort_t* __restrict__ Mout)
{
    const int lane = threadIdx.x & 63;
    const int wave = blockIdx.x * (blockDim.x >> 6) + (threadIdx.x >> 6);
    const int nwaves = gridDim.x * (blockDim.x >> 6);
    const int coff = lane * 2;

    for (int n = wave; n < NN; n += nwaves) {
        const int b = __builtin_amdgcn_readfirstlane(row_ptr[n]);
        const int e = __builtin_amdgcn_readfirstlane(row_ptr[n + 1]);
        const int deg = e - b;
        float accx = 0.0f, accy = 0.0f;
        int j = b;
        for (; j + 8 <= e; j += 8) {
            const int s0 = col[j + 0];
            const int s1 = col[j + 1];
            const int s2 = col[j + 2];
            const int s3 = col[j + 3];
            const int s4 = col[j + 4];
            const int s5 = col[j + 5];
            const int s6 = col[j + 6];
            const int s7 = col[j + 7];
            const unsigned int v0 = *(const unsigned int*)(F + (size_t)s0 * HIDC + coff);
            const unsigned int v1 = *(const unsigned int*)(F + (size_t)s1 * HIDC + coff);
            const unsigned int v2 = *(const unsigned int*)(F + (size_t)s2 * HIDC + coff);
            const unsigned int v3 = *(const unsigned int*)(F + (size_t)s3 * HIDC + coff);
            const unsigned int v4 = *(const unsigned int*)(F + (size_t)s4 * HIDC + coff);
            const unsigned int v5 = *(const unsigned int*)(F + (size_t)s5 * HIDC + coff);
            const unsigned int v6 = *(const unsigned int*)(F + (size_t)s6 * HIDC + coff);
            const unsigned int v7 = *(const unsigned int*)(F + (size_t)s7 * HIDC + coff);
            accx += bf2f(v0 & 0xffffu) + bf2f(v1 & 0xffffu) + bf2f(v2 & 0xffffu)
                  + bf2f(v3 & 0xffffu) + bf2f(v4 & 0xffffu) + bf2f(v5 & 0xffffu)
                  + bf2f(v6 & 0xffffu) + bf2f(v7 & 0xffffu);
            accy += bf2f(v0 >> 16) + bf2f(v1 >> 16) + bf2f(v2 >> 16)
                  + bf2f(v3 >> 16) + bf2f(v4 >> 16) + bf2f(v5 >> 16)
                  + bf2f(v6 >> 16) + bf2f(v7 >> 16);
        }
        for (; j < e; j++) {
            const int s = col[j];
            const unsigned int v = *(const unsigned int*)(F + (size_t)s * HIDC + coff);
            accx += bf2f(v & 0xffffu);
            accy += bf2f(v >> 16);
        }
        const float inv = 1.0f / (float)(deg > 1 ? deg : 1);
        *(unsigned int*)(Mout + (size_t)n * HIDC + coff) =
            pack2(accx * inv, accy * inv);
    }
}

// ---------------------------------------------------------------------------
extern "C" void kernel_launch(void* const* d_in, const int* in_sizes, int n_in,
                              void* d_out, int out_size, void* d_ws, size_t ws_size,
                              hipStream_t stream)
{
    const float* x     = (const float*)d_in[0];
    const int*   ei    = (const int*)  d_in[1];
    const float* W_in  = (const float*)d_in[2];
    const float* b_in  = (const float*)d_in[3];
    const float* g1    = (const float*)d_in[4];
    const float* be1   = (const float*)d_in[5];
    const float* W_hid = (const float*)d_in[6];
    const float* b_hid = (const float*)d_in[7];
    const float* g2    = (const float*)d_in[8];
    const float* be2   = (const float*)d_in[9];
    const float* Wl1   = (const float*)d_in[10];
    const float* bl1   = (const float*)d_in[11];
    const float* Wr1   = (const float*)d_in[12];
    const float* g3    = (const float*)d_in[13];
    const float* be3   = (const float*)d_in[14];
    const float* Wl2   = (const float*)d_in[15];
    const float* bl2   = (const float*)d_in[16];
    const float* Wr2   = (const float*)d_in[17];
    const float* g4    = (const float*)d_in[18];
    const float* be4   = (const float*)d_in[19];

    const int* srcArr = ei;        // edge_index[0]
    const int* dstArr = ei + EE;   // edge_index[1]

    char* ws = (char*)d_ws;
    float*    bufA      = (float*)ws;    ws += (size_t)NN * HIDC * sizeof(float);
    float*    bufB      = (float*)ws;    ws += (size_t)NN * HIDC * sizeof(float);
    ushort_t* featB16   = (ushort_t*)ws; ws += (size_t)NN * HIDC * sizeof(ushort_t);
    ushort_t* o3B16     = (ushort_t*)ws; ws += (size_t)NN * HIDC * sizeof(ushort_t);
    ushort_t* aggB16    = (ushort_t*)ws; ws += (size_t)NN * HIDC * sizeof(ushort_t);
    float*    stats     = (float*)ws;    ws += 4 * 256 * sizeof(float);
    int*      deg8      = (int*)ws;      ws += (size_t)8 * NN * sizeof(int);
    int*      cum8      = (int*)ws;      ws += (size_t)8 * NN * sizeof(int);
    int*      deg       = (int*)ws;      ws += (size_t)NN * sizeof(int);
    int*      rowp      = (int*)ws;      ws += (size_t)(NN + 4) * sizeof(int);
    int*      colIdx    = (int*)ws;      ws += (size_t)EE * sizeof(int);
    int*      tmpScan   = (int*)ws;      ws += (size_t)NN * sizeof(int);
    int*      blockSums = (int*)ws;      ws += 256 * sizeof(int);
    int*      blockOffs = (int*)ws;      ws += 256 * sizeof(int);
    ushort_t* Wt_in     = (ushort_t*)ws; ws += 128 * 256 * sizeof(ushort_t);
    ushort_t* Wt_hid    = (ushort_t*)ws; ws += 128 * 128 * sizeof(ushort_t);
    ushort_t* Wtl1      = (ushort_t*)ws; ws += 128 * 128 * sizeof(ushort_t);
    ushort_t* Wtr1      = (ushort_t*)ws; ws += 128 * 128 * sizeof(ushort_t);
    ushort_t* Wtl2      = (ushort_t*)ws; ws += 128 * 128 * sizeof(ushort_t);
    ushort_t* Wtr2      = (ushort_t*)ws; ws += 128 * 128 * sizeof(ushort_t);
    // rank aliases bufA: CSR build (hist->scatter) fully precedes first bufA write
    int* rank = (int*)bufA;

    float* out0 = (float*)d_out;             // feat  [NN*HID] fp32
    float* out1 = out0 + (size_t)NN * HIDC;  // out   [NN*HID] fp32

    // zero: stats (4 KB) + deg8 (1.6 MB) — contiguous region, one memset
    hipMemsetAsync(stats, 0, 4 * 256 * sizeof(float) + (size_t)8 * NN * sizeof(int),
                   stream);

    // weight transpose + bf16 convert
    tcvt_kernel<<<128, 256, 0, stream>>>(W_in,  Wt_in,  256);
    tcvt_kernel<<<64,  256, 0, stream>>>(W_hid, Wt_hid, 128);
    tcvt_kernel<<<64,  256, 0, stream>>>(Wl1,   Wtl1,   128);
    tcvt_kernel<<<64,  256, 0, stream>>>(Wr1,   Wtr1,   128);
    tcvt_kernel<<<64,  256, 0, stream>>>(Wl2,   Wtl2,   128);
    tcvt_kernel<<<64,  256, 0, stream>>>(Wr2,   Wtr2,   128);

    // CSR build (XCD-sharded histogram)
    hist_kernel<<<2048, 256, 0, stream>>>(dstArr, deg8, rank);
    const int nScanB = (NN + 255) / 256;   // 196
    cumdeg_kernel<<<nScanB, 256, 0, stream>>>(deg8, deg, cum8);
    scanA_kernel<<<nScanB, 256, 0, stream>>>(deg, tmpScan, blockSums);
    scanB_kernel<<<1, 256, 0, stream>>>(blockSums, blockOffs, rowp, nScanB);
    scanC_kernel<<<nScanB, 256, 0, stream>>>(tmpScan, deg, blockOffs, rowp);
    scatter_kernel<<<2048, 256, 0, stream>>>(srcArr, dstArr, rank, rowp, cum8, colIdx);

    const int gemmGrid = (NN + 63) / 64;   // 782

    // stage 1: input linear (x fp32, K=256) -> bufA fp32 + stats0
    mfma_gemm_kernel<<<gemmGrid, 256, 0, stream>>>(
        x, Wt_in, IN_DIMC, 0, nullptr, nullptr, 0,
        b_in, bufA, NN, nullptr, nullptr, nullptr, stats + 0);

    // stage 2: hidden linear, BN1+relu fused on A-load -> bufB fp32 + stats1
    mfma_gemm_kernel<<<gemmGrid, 256, 0, stream>>>(
        bufA, Wt_hid, HIDC, 0, nullptr, nullptr, 0,
        b_hid, bufB, NN, stats + 0, g1, be1, stats + 256);

    // BN2+relu -> out0 (fp32) + featB16 (bf16)
    bn_apply_kernel<<<1024, 256, 0, stream>>>(bufB, out0, featB16,
                                              stats + 256, g2, be2, 1, NN);

    // stage 3: SAGE1
    agg_kernel<<<4096, 256, 0, stream>>>(featB16, rowp, colIdx, aggB16);
    mfma_gemm_kernel<<<gemmGrid, 256, 0, stream>>>(
        aggB16, Wtl1, HIDC, 1, featB16, Wtr1, HIDC,
        bl1, bufA, NN, nullptr, nullptr, nullptr, stats + 512);

    // BN3 -> o3B16 (bf16 only)
    bn_apply_kernel<<<1024, 256, 0, stream>>>(bufA, nullptr, o3B16,
                                              stats + 512, g3, be3, 0, NN);

    // stage 4: SAGE2
    agg_kernel<<<4096, 256, 0, stream>>>(o3B16, rowp, colIdx, aggB16);
    mfma_gemm_kernel<<<gemmGrid, 256, 0, stream>>>(
        aggB16, Wtl2, HIDC, 1, o3B16, Wtr2, HIDC,
        bl2, bufB, NN, nullptr, nullptr, nullptr, stats + 768);

    // BN4 -> out1 (fp32)
    bn_apply_kernel<<<1024, 256, 0, stream>>>(bufB, out1, nullptr,
                                              stats + 768, g4, be4, 0, NN);
}

// Round 5
// 475.065 us; speedup vs baseline: 2.5975x; 1.0548x over previous
//
#include <hip/hip_runtime.h>
#include <stdint.h>

#define NN 50000
#define EE 1600000
#define IN_DIMC 256
#define HIDC 128
#define EPSC 1e-5f

// counting-sort geometry
#define NB 196        // coarse buckets: dst>>8, 256 nodes/bucket (196*256 >= 50000)
#define GA 512        // phase-A blocks
#define CHUNK 3125    // EE / GA exactly

typedef unsigned short ushort_t;
typedef __attribute__((ext_vector_type(8))) short short8;
typedef __attribute__((ext_vector_type(4))) float floatx4;

static __device__ inline ushort_t f2bf(float f) {
    unsigned int u = __float_as_uint(f);
    u = u + 0x7fffu + ((u >> 16) & 1u);   // RNE
    return (ushort_t)(u >> 16);
}
static __device__ inline unsigned int pack2(float a, float b) {
    return (unsigned int)f2bf(a) | ((unsigned int)f2bf(b) << 16);
}
static __device__ inline float bf2f(unsigned int bits16) {
    return __uint_as_float(bits16 << 16);
}

// ---------------------------------------------------------------------------
// All six weight transposes + bf16 convert in ONE launch.
// Wt[n][k] = bf16(W[k][n]); W is [K][128].
// Segment 0: W_in (K=256, 32768 elems); segments 1..5: K=128 (16384 each).
// ---------------------------------------------------------------------------
__global__ __launch_bounds__(256) void tcvt_all_kernel(
    const float* __restrict__ W_in, const float* __restrict__ W_hid,
    const float* __restrict__ Wl1, const float* __restrict__ Wr1,
    const float* __restrict__ Wl2, const float* __restrict__ Wr2,
    ushort_t* __restrict__ Wt_in, ushort_t* __restrict__ Wt_hid,
    ushort_t* __restrict__ Wtl1, ushort_t* __restrict__ Wtr1,
    ushort_t* __restrict__ Wtl2, ushort_t* __restrict__ Wtr2)
{
    const int idx = blockIdx.x * 256 + threadIdx.x;
    if (idx < 32768) {
        const int n = idx >> 8;           // /256
        const int k = idx & 255;
        Wt_in[idx] = f2bf(W_in[(size_t)k * 128 + n]);
    } else if (idx < 32768 + 5 * 16384) {
        const int r = idx - 32768;
        const int seg = r / 16384;
        const int j = r - seg * 16384;
        const int n = j >> 7;
        const int k = j & 127;
        const float* W; ushort_t* Wt;
        switch (seg) {
            case 0: W = W_hid; Wt = Wt_hid; break;
            case 1: W = Wl1;  Wt = Wtl1;  break;
            case 2: W = Wr1;  Wt = Wtr1;  break;
            case 3: W = Wl2;  Wt = Wtl2;  break;
            default: W = Wr2; Wt = Wtr2;  break;
        }
        Wt[j] = f2bf(W[(size_t)k * 128 + n]);
    }
}

// ---------------------------------------------------------------------------
// MFMA GEMM: C[M,128] = A1@W1 (+ A2@W2) + bias, fp32 accum, bf16 inputs.
// (unchanged — verified in rounds 3/4)
// ---------------------------------------------------------------------------
__global__ __launch_bounds__(256) void mfma_gemm_kernel(
    const void* __restrict__ A1, const ushort_t* __restrict__ Wt1, int K1, int a1type,
    const void* __restrict__ A2, const ushort_t* __restrict__ Wt2, int K2,
    const float* __restrict__ bias, float* __restrict__ C, int M,
    const float* __restrict__ preStats, const float* __restrict__ preG,
    const float* __restrict__ preBe, float* __restrict__ outStats)
{
    __shared__ ushort_t As[64 * 72];
    __shared__ ushort_t Bs[128 * 72];
    __shared__ float aArr[128], bArr[128];
    __shared__ float red_s[4][64], red_q[4][64];

    const int t     = threadIdx.x;
    const int lane  = t & 63;
    const int wave  = t >> 6;
    const int quad  = lane >> 4;
    const int l15   = lane & 15;
    const int mhalf = wave & 1;
    const int nhalf = wave >> 1;
    const int row0  = blockIdx.x * 64;
    const int doAffine = (preStats != nullptr);

    if (doAffine && t < 128) {
        const float invM = 1.0f / (float)M;
        const float mean = preStats[t] * invM;
        float var = preStats[128 + t] * invM - mean * mean;
        if (var < 0.0f) var = 0.0f;
        const float s = preG[t] / sqrtf(var + EPSC);
        aArr[t] = s;
        bArr[t] = preBe[t] - mean * s;
    }
    if (doAffine) __syncthreads();

    floatx4 acc[2][4];
    #pragma unroll
    for (int i = 0; i < 2; i++)
        #pragma unroll
        for (int j = 0; j < 4; j++)
            acc[i][j] = (floatx4){0.0f, 0.0f, 0.0f, 0.0f};

    for (int s = 0; s < 2; s++) {
        const void*     A     = s ? A2  : A1;
        const ushort_t* Wt    = s ? Wt2 : Wt1;
        const int       K     = s ? K2  : K1;
        const int       atype = s ? 1   : a1type;
        if (A == nullptr) continue;

        for (int kc = 0; kc < K; kc += 64) {
            #pragma unroll
            for (int p = 0; p < 2; p++) {
                const int idx = p * 256 + t;
                const int r   = idx >> 3;
                const int c0  = (idx & 7) * 8;
                int gr = row0 + r;
                if (gr > M - 1) gr = M - 1;
                if (atype == 0) {
                    const float* Af = (const float*)A;
                    const size_t base = (size_t)gr * K + kc + c0;
                    float4 v0 = *(const float4*)(Af + base);
                    float4 v1 = *(const float4*)(Af + base + 4);
                    if (doAffine && s == 0) {
                        const int k0 = kc + c0;
                        v0.x = fmaxf(aArr[k0]     * v0.x + bArr[k0],     0.0f);
                        v0.y = fmaxf(aArr[k0 + 1] * v0.y + bArr[k0 + 1], 0.0f);
                        v0.z = fmaxf(aArr[k0 + 2] * v0.z + bArr[k0 + 2], 0.0f);
                        v0.w = fmaxf(aArr[k0 + 3] * v0.w + bArr[k0 + 3], 0.0f);
                        v1.x = fmaxf(aArr[k0 + 4] * v1.x + bArr[k0 + 4], 0.0f);
                        v1.y = fmaxf(aArr[k0 + 5] * v1.y + bArr[k0 + 5], 0.0f);
                        v1.z = fmaxf(aArr[k0 + 6] * v1.z + bArr[k0 + 6], 0.0f);
                        v1.w = fmaxf(aArr[k0 + 7] * v1.w + bArr[k0 + 7], 0.0f);
                    }
                    uint4 w;
                    w.x = pack2(v0.x, v0.y);
                    w.y = pack2(v0.z, v0.w);
                    w.z = pack2(v1.x, v1.y);
                    w.w = pack2(v1.z, v1.w);
                    *(uint4*)(As + r * 72 + c0) = w;
                } else {
                    const ushort_t* Ab = (const ushort_t*)A;
                    *(uint4*)(As + r * 72 + c0) =
                        *(const uint4*)(Ab + (size_t)gr * K + kc + c0);
                }
            }
            #pragma unroll
            for (int p = 0; p < 4; p++) {
                const int idx = p * 256 + t;
                const int n   = idx >> 3;
                const int c0  = (idx & 7) * 8;
                *(uint4*)(Bs + n * 72 + c0) =
                    *(const uint4*)(Wt + (size_t)n * K + kc + c0);
            }
            __syncthreads();

            #pragma unroll
            for (int ks = 0; ks < 2; ks++) {
                const int ko = ks * 32 + quad * 8;
                const short8 a0 = *(const short8*)(As + (mhalf * 32 + l15) * 72 + ko);
                const short8 a1 = *(const short8*)(As + (mhalf * 32 + 16 + l15) * 72 + ko);
                short8 b[4];
                #pragma unroll
                for (int j = 0; j < 4; j++)
                    b[j] = *(const short8*)(Bs + (nhalf * 64 + j * 16 + l15) * 72 + ko);
                #pragma unroll
                for (int j = 0; j < 4; j++) {
                    acc[0][j] = __builtin_amdgcn_mfma_f32_16x16x32_bf16(a0, b[j], acc[0][j], 0, 0, 0);
                    acc[1][j] = __builtin_amdgcn_mfma_f32_16x16x32_bf16(a1, b[j], acc[1][j], 0, 0, 0);
                }
            }
            __syncthreads();
        }
    }

    float s_[4], q_[4];
    #pragma unroll
    for (int j = 0; j < 4; j++) { s_[j] = 0.0f; q_[j] = 0.0f; }

    #pragma unroll
    for (int j = 0; j < 4; j++) {
        const int col = nhalf * 64 + j * 16 + l15;
        const float bv = bias[col];
        #pragma unroll
        for (int i = 0; i < 2; i++) {
            const int rbase = row0 + mhalf * 32 + i * 16 + quad * 4;
            #pragma unroll
            for (int reg = 0; reg < 4; reg++) {
                const float val = acc[i][j][reg] + bv;
                const int r_ = rbase + reg;
                if (r_ < M) {
                    C[(size_t)r_ * HIDC + col] = val;
                    s_[j] += val;
                    q_[j] += val * val;
                }
            }
        }
    }
    #pragma unroll
    for (int j = 0; j < 4; j++) {
        s_[j] += __shfl_xor(s_[j], 16, 64);
        s_[j] += __shfl_xor(s_[j], 32, 64);
        q_[j] += __shfl_xor(q_[j], 16, 64);
        q_[j] += __shfl_xor(q_[j], 32, 64);
    }
    if (quad == 0) {
        #pragma unroll
        for (int j = 0; j < 4; j++) {
            red_s[wave][j * 16 + l15] = s_[j];
            red_q[wave][j * 16 + l15] = q_[j];
        }
    }
    __syncthreads();
    if (t < 128) {
        const int c = t;
        const int g = c >> 6;
        const int cc = c & 63;
        const float S = red_s[g * 2][cc] + red_s[g * 2 + 1][cc];
        const float Q = red_q[g * 2][cc] + red_q[g * 2 + 1][cc];
        atomicAdd(&outStats[c], S);
        atomicAdd(&outStats[128 + c], Q);
    }
}

// ---------------------------------------------------------------------------
// BN apply: dst fp32 (optional) and/or dst bf16 (optional), + optional relu
// ---------------------------------------------------------------------------
__global__ __launch_bounds__(256) void bn_apply_kernel(
    const float* __restrict__ src, float* __restrict__ dstF,
    ushort_t* __restrict__ dstB, const float* __restrict__ stats,
    const float* __restrict__ gamma, const float* __restrict__ beta,
    int relu, int M)
{
    __shared__ float sc[128], sh[128];
    const int t = threadIdx.x;
    if (t < 128) {
        const float invM = 1.0f / (float)M;
        const float mean = stats[t] * invM;
        float var = stats[128 + t] * invM - mean * mean;
        if (var < 0.0f) var = 0.0f;
        const float s = gamma[t] / sqrtf(var + EPSC);
        sc[t] = s;
        sh[t] = beta[t] - mean * s;
    }
    __syncthreads();

    const int total4 = M * HIDC / 4;
    for (int i = blockIdx.x * 256 + t; i < total4; i += gridDim.x * 256) {
        float4 v = ((const float4*)src)[i];
        const int c = (i * 4) & 127;
        v.x = v.x * sc[c]     + sh[c];
        v.y = v.y * sc[c + 1] + sh[c + 1];
        v.z = v.z * sc[c + 2] + sh[c + 2];
        v.w = v.w * sc[c + 3] + sh[c + 3];
        if (relu) {
            v.x = fmaxf(v.x, 0.0f); v.y = fmaxf(v.y, 0.0f);
            v.z = fmaxf(v.z, 0.0f); v.w = fmaxf(v.w, 0.0f);
        }
        if (dstF) ((float4*)dstF)[i] = v;
        if (dstB) {
            uint2 w;
            w.x = pack2(v.x, v.y);
            w.y = pack2(v.z, v.w);
            *(uint2*)(dstB + (size_t)i * 4) = w;
        }
    }
}

// ---------------------------------------------------------------------------
// CSR build — atomic-free two-level counting sort (no stability needed: mean
// aggregation is order-invariant within a dst).
//
// A0: per-block LDS histogram over NB coarse buckets -> hist2D[NB][GA] (stores)
// A0.5: one block: in-bucket running offsets (over blocks) + bucket base scan
// A1: re-read edges, place (src,dst) into bucket-segmented ebuf via LDS cursors
//     seeded from deterministic global offsets (LDS atomics only)
// B: one block per bucket: LDS count(256) -> scan -> rowp + col scatter into an
//    L2-resident 32KB window (LDS atomics only)
// ---------------------------------------------------------------------------
__global__ __launch_bounds__(256) void bucket_hist_kernel(
    const int* __restrict__ dstArr, int* __restrict__ hist2D)
{
    __shared__ int hist[NB];
    const int t = threadIdx.x;
    for (int i = t; i < NB; i += 256) hist[i] = 0;
    __syncthreads();
    const int e0 = blockIdx.x * CHUNK;
    const int e1 = e0 + CHUNK;   // EE = GA*CHUNK exactly
    for (int e = e0 + t; e < e1; e += 256)
        atomicAdd(&hist[dstArr[e] >> 8], 1);
    __syncthreads();
    for (int i = t; i < NB; i += 256)
        hist2D[(size_t)i * GA + blockIdx.x] = hist[i];
}

__global__ __launch_bounds__(256) void bucket_offsets_kernel(
    int* __restrict__ hist2D, int* __restrict__ bucketBase, int* __restrict__ rowp)
{
    __shared__ int wtot[4];
    const int t = threadIdx.x;
    int tot = 0;
    if (t < NB) {
        int4* p = (int4*)(hist2D + (size_t)t * GA);
        int s = 0;
        for (int i = 0; i < GA / 4; i++) {
            int4 h = p[i];
            int4 o;
            o.x = s; s += h.x;
            o.y = s; s += h.y;
            o.z = s; s += h.z;
            o.w = s; s += h.w;
            p[i] = o;
        }
        tot = s;
    }
    // exclusive scan of tot across 256 threads
    const int lane = t & 63, w = t >> 6;
    int x = tot;
    #pragma unroll
    for (int off = 1; off < 64; off <<= 1) {
        const int y = __shfl_up(x, off);
        if (lane >= off) x += y;
    }
    if (lane == 63) wtot[w] = x;
    __syncthreads();
    int woff = 0;
    #pragma unroll
    for (int j = 0; j < 4; j++) if (j < w) woff += wtot[j];
    const int excl = x + woff - tot;
    if (t < NB) bucketBase[t] = excl;
    if (t == 0) { bucketBase[NB] = EE; rowp[NN] = EE; }
}

__global__ __launch_bounds__(256) void bucket_scatter_kernel(
    const int* __restrict__ srcArr, const int* __restrict__ dstArr,
    const int* __restrict__ hist2D, const int* __restrict__ bucketBase,
    int2* __restrict__ ebuf)
{
    __shared__ int cur[NB];
    const int t = threadIdx.x;
    for (int i = t; i < NB; i += 256)
        cur[i] = bucketBase[i] + hist2D[(size_t)i * GA + blockIdx.x];
    __syncthreads();
    const int e0 = blockIdx.x * CHUNK;
    const int e1 = e0 + CHUNK;
    for (int e = e0 + t; e < e1; e += 256) {
        const int d = dstArr[e];
        const int s = srcArr[e];
        const int p = atomicAdd(&cur[d >> 8], 1);
        ebuf[p] = make_int2(s, d);
    }
}

__global__ __launch_bounds__(256) void fine_sort_kernel(
    const int2* __restrict__ ebuf, const int* __restrict__ bucketBase,
    int* __restrict__ rowp, int* __restrict__ col)
{
    __shared__ int cnt[256];
    __shared__ int wtot[4];
    const int b = blockIdx.x;
    const int t = threadIdx.x;
    const int bb0 = bucketBase[b];
    const int bb1 = bucketBase[b + 1];
    cnt[t] = 0;
    __syncthreads();
    for (int e = bb0 + t; e < bb1; e += 256)
        atomicAdd(&cnt[ebuf[e].y & 255], 1);
    __syncthreads();
    // exclusive scan of cnt[256]
    const int lane = t & 63, w = t >> 6;
    const int v = cnt[t];
    int x = v;
    #pragma unroll
    for (int off = 1; off < 64; off <<= 1) {
        const int y = __shfl_up(x, off);
        if (lane >= off) x += y;
    }
    if (lane == 63) wtot[w] = x;
    __syncthreads();
    int woff = 0;
    #pragma unroll
    for (int j = 0; j < 4; j++) if (j < w) woff += wtot[j];
    const int excl = x + woff - v;
    const int node = b * 256 + t;
    if (node < NN) rowp[node] = bb0 + excl;
    __syncthreads();
    cnt[t] = excl;     // reuse as local cursor
    __syncthreads();
    for (int e = bb0 + t; e < bb1; e += 256) {
        const int2 sd = ebuf[e];
        const int p = atomicAdd(&cnt[sd.y & 255], 1);
        col[bb0 + p] = sd.x;
    }
}

// ---------------------------------------------------------------------------
// Mean aggregation over bf16 features: one wave per node, 2 cols/lane (4 B).
// Wave-uniform CSR bounds in SGPRs; unroll 8 keeps 8 gathers in flight.
// ---------------------------------------------------------------------------
__global__ __launch_bounds__(256) void agg_kernel(
    const ushort_t* __restrict__ F, const int* __restrict__ row_ptr,
    const int* __restrict__ col, ushort_t* __restrict__ Mout)
{
    const int lane = threadIdx.x & 63;
    const int wave = blockIdx.x * (blockDim.x >> 6) + (threadIdx.x >> 6);
    const int nwaves = gridDim.x * (blockDim.x >> 6);
    const int coff = lane * 2;

    for (int n = wave; n < NN; n += nwaves) {
        const int b = __builtin_amdgcn_readfirstlane(row_ptr[n]);
        const int e = __builtin_amdgcn_readfirstlane(row_ptr[n + 1]);
        const int deg = e - b;
        float accx = 0.0f, accy = 0.0f;
        int j = b;
        for (; j + 8 <= e; j += 8) {
            const int s0 = col[j + 0];
            const int s1 = col[j + 1];
            const int s2 = col[j + 2];
            const int s3 = col[j + 3];
            const int s4 = col[j + 4];
            const int s5 = col[j + 5];
            const int s6 = col[j + 6];
            const int s7 = col[j + 7];
            const unsigned int v0 = *(const unsigned int*)(F + (size_t)s0 * HIDC + coff);
            const unsigned int v1 = *(const unsigned int*)(F + (size_t)s1 * HIDC + coff);
            const unsigned int v2 = *(const unsigned int*)(F + (size_t)s2 * HIDC + coff);
            const unsigned int v3 = *(const unsigned int*)(F + (size_t)s3 * HIDC + coff);
            const unsigned int v4 = *(const unsigned int*)(F + (size_t)s4 * HIDC + coff);
            const unsigned int v5 = *(const unsigned int*)(F + (size_t)s5 * HIDC + coff);
            const unsigned int v6 = *(const unsigned int*)(F + (size_t)s6 * HIDC + coff);
            const unsigned int v7 = *(const unsigned int*)(F + (size_t)s7 * HIDC + coff);
            accx += bf2f(v0 & 0xffffu) + bf2f(v1 & 0xffffu) + bf2f(v2 & 0xffffu)
                  + bf2f(v3 & 0xffffu) + bf2f(v4 & 0xffffu) + bf2f(v5 & 0xffffu)
                  + bf2f(v6 & 0xffffu) + bf2f(v7 & 0xffffu);
            accy += bf2f(v0 >> 16) + bf2f(v1 >> 16) + bf2f(v2 >> 16)
                  + bf2f(v3 >> 16) + bf2f(v4 >> 16) + bf2f(v5 >> 16)
                  + bf2f(v6 >> 16) + bf2f(v7 >> 16);
        }
        for (; j < e; j++) {
            const int s = col[j];
            const unsigned int v = *(const unsigned int*)(F + (size_t)s * HIDC + coff);
            accx += bf2f(v & 0xffffu);
            accy += bf2f(v >> 16);
        }
        const float inv = 1.0f / (float)(deg > 1 ? deg : 1);
        *(unsigned int*)(Mout + (size_t)n * HIDC + coff) =
            pack2(accx * inv, accy * inv);
    }
}

// ---------------------------------------------------------------------------
extern "C" void kernel_launch(void* const* d_in, const int* in_sizes, int n_in,
                              void* d_out, int out_size, void* d_ws, size_t ws_size,
                              hipStream_t stream)
{
    const float* x     = (const float*)d_in[0];
    const int*   ei    = (const int*)  d_in[1];
    const float* W_in  = (const float*)d_in[2];
    const float* b_in  = (const float*)d_in[3];
    const float* g1    = (const float*)d_in[4];
    const float* be1   = (const float*)d_in[5];
    const float* W_hid = (const float*)d_in[6];
    const float* b_hid = (const float*)d_in[7];
    const float* g2    = (const float*)d_in[8];
    const float* be2   = (const float*)d_in[9];
    const float* Wl1   = (const float*)d_in[10];
    const float* bl1   = (const float*)d_in[11];
    const float* Wr1   = (const float*)d_in[12];
    const float* g3    = (const float*)d_in[13];
    const float* be3   = (const float*)d_in[14];
    const float* Wl2   = (const float*)d_in[15];
    const float* bl2   = (const float*)d_in[16];
    const float* Wr2   = (const float*)d_in[17];
    const float* g4    = (const float*)d_in[18];
    const float* be4   = (const float*)d_in[19];

    const int* srcArr = ei;        // edge_index[0]
    const int* dstArr = ei + EE;   // edge_index[1]

    char* ws = (char*)d_ws;
    float*    bufA      = (float*)ws;    ws += (size_t)NN * HIDC * sizeof(float);
    float*    bufB      = (float*)ws;    ws += (size_t)NN * HIDC * sizeof(float);
    ushort_t* featB16   = (ushort_t*)ws; ws += (size_t)NN * HIDC * sizeof(ushort_t);
    ushort_t* o3B16     = (ushort_t*)ws; ws += (size_t)NN * HIDC * sizeof(ushort_t);
    ushort_t* aggB16    = (ushort_t*)ws; ws += (size_t)NN * HIDC * sizeof(ushort_t);
    float*    stats     = (float*)ws;    ws += 4 * 256 * sizeof(float);
    int*      hist2D    = (int*)ws;      ws += (size_t)NB * GA * sizeof(int);
    int*      bucketBase= (int*)ws;      ws += (NB + 4) * sizeof(int);
    int*      rowp      = (int*)ws;      ws += (size_t)(NN + 4) * sizeof(int);
    int*      colIdx    = (int*)ws;      ws += (size_t)EE * sizeof(int);
    int2*     ebuf      = (int2*)ws;     ws += (size_t)EE * sizeof(int2);
    ushort_t* Wt_in     = (ushort_t*)ws; ws += 128 * 256 * sizeof(ushort_t);
    ushort_t* Wt_hid    = (ushort_t*)ws; ws += 128 * 128 * sizeof(ushort_t);
    ushort_t* Wtl1      = (ushort_t*)ws; ws += 128 * 128 * sizeof(ushort_t);
    ushort_t* Wtr1      = (ushort_t*)ws; ws += 128 * 128 * sizeof(ushort_t);
    ushort_t* Wtl2      = (ushort_t*)ws; ws += 128 * 128 * sizeof(ushort_t);
    ushort_t* Wtr2      = (ushort_t*)ws; ws += 128 * 128 * sizeof(ushort_t);

    float* out0 = (float*)d_out;             // feat  [NN*HID] fp32
    float* out1 = out0 + (size_t)NN * HIDC;  // out   [NN*HID] fp32

    // zero: stats only (counting sort is store-based, nothing else needs init)
    hipMemsetAsync(stats, 0, 4 * 256 * sizeof(float), stream);

    // weight transpose + bf16 convert (one launch, 448 blocks)
    tcvt_all_kernel<<<448, 256, 0, stream>>>(W_in, W_hid, Wl1, Wr1, Wl2, Wr2,
                                             Wt_in, Wt_hid, Wtl1, Wtr1, Wtl2, Wtr2);

    // CSR build — atomic-free counting sort
    bucket_hist_kernel<<<GA, 256, 0, stream>>>(dstArr, hist2D);
    bucket_offsets_kernel<<<1, 256, 0, stream>>>(hist2D, bucketBase, rowp);
    bucket_scatter_kernel<<<GA, 256, 0, stream>>>(srcArr, dstArr, hist2D,
                                                  bucketBase, ebuf);
    fine_sort_kernel<<<NB, 256, 0, stream>>>(ebuf, bucketBase, rowp, colIdx);

    const int gemmGrid = (NN + 63) / 64;   // 782

    // stage 1: input linear (x fp32, K=256) -> bufA fp32 + stats0
    mfma_gemm_kernel<<<gemmGrid, 256, 0, stream>>>(
        x, Wt_in, IN_DIMC, 0, nullptr, nullptr, 0,
        b_in, bufA, NN, nullptr, nullptr, nullptr, stats + 0);

    // stage 2: hidden linear, BN1+relu fused on A-load -> bufB fp32 + stats1
    mfma_gemm_kernel<<<gemmGrid, 256, 0, stream>>>(
        bufA, Wt_hid, HIDC, 0, nullptr, nullptr, 0,
        b_hid, bufB, NN, stats + 0, g1, be1, stats + 256);

    // BN2+relu -> out0 (fp32) + featB16 (bf16)
    bn_apply_kernel<<<1024, 256, 0, stream>>>(bufB, out0, featB16,
                                              stats + 256, g2, be2, 1, NN);

    // stage 3: SAGE1
    agg_kernel<<<4096, 256, 0, stream>>>(featB16, rowp, colIdx, aggB16);
    mfma_gemm_kernel<<<gemmGrid, 256, 0, stream>>>(
        aggB16, Wtl1, HIDC, 1, featB16, Wtr1, HIDC,
        bl1, bufA, NN, nullptr, nullptr, nullptr, stats + 512);

    // BN3 -> o3B16 (bf16 only)
    bn_apply_kernel<<<1024, 256, 0, stream>>>(bufA, nullptr, o3B16,
                                              stats + 512, g3, be3, 0, NN);

    // stage 4: SAGE2
    agg_kernel<<<4096, 256, 0, stream>>>(o3B16, rowp, colIdx, aggB16);
    mfma_gemm_kernel<<<gemmGrid, 256, 0, stream>>>(
        aggB16, Wtl2, HIDC, 1, o3B16, Wtr2, HIDC,
        bl2, bufB, NN, nullptr, nullptr, nullptr, stats + 768);

    // BN4 -> out1 (fp32)
    bn_apply_kernel<<<1024, 256, 0, stream>>>(bufB, out1, nullptr,
                                              stats + 768, g4, be4, 0, NN);
}